// Round 8
// baseline (1338.979 us; speedup 1.0000x reference)
//
#include <hip/hip_runtime.h>
#include <hip/hip_bf16.h>

typedef __bf16 v8bf  __attribute__((ext_vector_type(8)));
typedef __bf16 v4bf  __attribute__((ext_vector_type(4)));
typedef float  f32x4 __attribute__((ext_vector_type(4)));
typedef float  f32x8 __attribute__((ext_vector_type(8)));

#define TOKENS 50176
#define CDIM   576
#define NHEAD  18
#define QKVD   1728

// async global->LDS, 16B per lane; LDS dest = wave-uniform base + lane*16
__device__ __forceinline__ void gld16(const __bf16* g, __bf16* l)
{
    __builtin_amdgcn_global_load_lds(
        (const __attribute__((address_space(1))) void*)g,
        (__attribute__((address_space(3))) void*)l,
        16, 0, 0);
}

// exact-GELU via Abramowitz-Stegun 7.1.26 erf (|err| <= 1.5e-7, far below bf16 eps)
__device__ __forceinline__ float fast_gelu(float x)
{
    const float z  = x * 0.70710678118654752f;
    const float az = fabsf(z);
    const float t  = __frcp_rn(1.0f + 0.3275911f * az);
    float p = 1.061405429f;
    p = p * t - 1.453152027f;
    p = p * t + 1.421413741f;
    p = p * t - 0.284496736f;
    p = p * t + 0.254829592f;
    const float e   = __expf(-z * z);
    float erfv = 1.0f - p * t * e;
    erfv = copysignf(erfv, z);
    return 0.5f * x * (1.0f + erfv);
}

// ---------------- f32 -> bf16 cast (weights), 4 elems/thread ----------------
__global__ __launch_bounds__(256)
void cast_kernel(const float* __restrict__ in, __bf16* __restrict__ out)
{
    const size_t i = ((size_t)blockIdx.x * 256 + threadIdx.x) * 4;
    f32x4 v = *(const f32x4*)&in[i];
    v4bf o;
#pragma unroll
    for (int j = 0; j < 4; ++j) o[j] = (__bf16)v[j];
    *(v4bf*)&out[i] = o;
}

// ------- conv weight prep: fold BN scale into weights, make [9][576] bf16 -------
__global__ __launch_bounds__(64)
void conv_prep(const float* __restrict__ w, const float* __restrict__ bg,
               const float* __restrict__ bb, const float* __restrict__ bm,
               const float* __restrict__ bv, __bf16* __restrict__ wt,
               float* __restrict__ bias2)
{
    const int c = blockIdx.x * 64 + threadIdx.x;   // 576
    const float inv = rsqrtf(bv[c] + 1e-5f) * bg[c];
#pragma unroll
    for (int t = 0; t < 9; ++t) wt[t * CDIM + c] = (__bf16)(w[c * 9 + t] * inv);
    bias2[c] = bb[c] - bm[c] * inv;
}

// ---------------- LayerNorm: one wave per token, C=576; InT in, bf16 out ----
template<typename InT>
__global__ __launch_bounds__(256)
void ln_kernel(const InT* __restrict__ x, const float* __restrict__ g,
               const float* __restrict__ b, __bf16* __restrict__ out)
{
    const int lane = threadIdx.x & 63;
    const int wid  = threadIdx.x >> 6;
    const size_t t = (size_t)blockIdx.x * 4 + wid;
    const InT* row = x + t * CDIM;

    float v[16];
    float sum = 0.f, sq = 0.f;
    if constexpr (sizeof(InT) == 2) {
        v8bf d0 = *(const v8bf*)&row[(size_t)lane * 8];
#pragma unroll
        for (int j = 0; j < 8; ++j) { float f = (float)d0[j]; v[j] = f; sum += f; sq += f * f; }
    } else {
        f32x8 d0 = *(const f32x8*)&row[(size_t)lane * 8];
#pragma unroll
        for (int j = 0; j < 8; ++j) { float f = d0[j]; v[j] = f; sum += f; sq += f * f; }
    }
    if (lane < 8) {
        if constexpr (sizeof(InT) == 2) {
            v8bf d1 = *(const v8bf*)&row[(size_t)(lane + 64) * 8];
#pragma unroll
            for (int j = 0; j < 8; ++j) { float f = (float)d1[j]; v[8 + j] = f; sum += f; sq += f * f; }
        } else {
            f32x8 d1 = *(const f32x8*)&row[(size_t)(lane + 64) * 8];
#pragma unroll
            for (int j = 0; j < 8; ++j) { float f = d1[j]; v[8 + j] = f; sum += f; sq += f * f; }
        }
    }
#pragma unroll
    for (int o = 32; o >= 1; o >>= 1) {
        sum += __shfl_xor(sum, o, 64);
        sq  += __shfl_xor(sq,  o, 64);
    }
    const float mean = sum * (1.0f / CDIM);
    const float rstd = rsqrtf(sq * (1.0f / CDIM) - mean * mean + 1e-5f);

    {
        int c0 = lane * 8;
        v8bf o0;
#pragma unroll
        for (int j = 0; j < 8; ++j)
            o0[j] = (__bf16)((v[j] - mean) * rstd * g[c0 + j] + b[c0 + j]);
        *(v8bf*)&out[t * CDIM + c0] = o0;
    }
    if (lane < 8) {
        int c0 = (lane + 64) * 8;
        v8bf o1;
#pragma unroll
        for (int j = 0; j < 8; ++j)
            o1[j] = (__bf16)((v[8 + j] - mean) * rstd * g[c0 + j] + b[c0 + j]);
        *(v8bf*)&out[t * CDIM + c0] = o1;
    }
}

// ------- GEMM: C[M][N] = A[M][K] @ W[N][K]^T + bias, optional epilogue -------
// BM=256, BN=64, BK=32; 256 threads, 4 waves stacked in M (wave tile 64x64).
// T3/T4 deep pipeline: ring-4 LDS (80KB -> 2 blocks/CU), DISTANCE-3 prefetch.
// At iter t we wait vmcnt(10): stage(t) was issued 3 iters (~2000cy) earlier,
// so the wait is ~0 in steady state; stages t+1,t+2 (10 loads) stay in flight
// across the barrier. One raw s_barrier per step; sched_barrier(0) only as the
// post-barrier fence (m201 pattern). Race-free: buf (t+3)%4 was read at t-1 and
// those reads were consumed (lgkm) before every wave passed barrier t.
// Sub-tiled LDS cells (16 rows)x16B: conflict-free ds_read_b128, linear
// global_load_lds dest. All N in {576,1728,2304} divide BN=64: no raggedness.
// EPI: 0 = none, 1 = += add[M][N], 2 = exact GELU
template<int EPI, typename OutT, typename AddT>
__global__ __launch_bounds__(256, 2)
void gemm_bt(const __bf16* __restrict__ A, const __bf16* __restrict__ W,
             const float* __restrict__ bias, const AddT* __restrict__ add,
             OutT* __restrict__ C, int N, int K, int nN)
{
    constexpr int BM = 256, BN = 64, BK = 32;
    __shared__ __bf16 As[4][BM * BK];   // 64 KB
    __shared__ __bf16 Ws[4][BN * BK];   // 16 KB
    const int tid = threadIdx.x, lane = tid & 63, wid = tid >> 6;
    const int lr = lane & 15, kh = lane >> 4;

    // XCD-chunked bijective swizzle (m204), N-fastest decode
    const int nwg = gridDim.x, bid = blockIdx.x;
    const int q = nwg >> 3, r = nwg & 7;
    const int xcd = bid & 7, jc = bid >> 3;
    const int wgid = (xcd < r ? xcd * (q + 1) : r * (q + 1) + (xcd - r) * q) + jc;
    const int mblk = wgid / nN, nblk = wgid - mblk * nN;
    const int m0 = mblk * BM, n0 = nblk * BN;

    // staging sources: wave wid covers A rows [wid*64,+64), W rows [wid*16,+16)
    const __bf16* pA = A + (size_t)(m0 + wid * 64 + lr) * K + kh * 8;
    const __bf16* pW = W + (size_t)(n0 + wid * 16 + lr) * K + kh * 8;

    // 5 gld16 per thread per stage (A:4, W:1)
    auto stage = [&](int s, int kt) {
        const int kk = kt * BK;
#pragma unroll
        for (int i = 0; i < 4; ++i)
            gld16(pA + (size_t)(i * 16) * K + kk, &As[s][(wid * 4 + i) * 512]);
        gld16(pW + kk, &Ws[s][wid * 512]);
    };

    const int off = (kh * 16 + lr) * 8;   // lane cell offset within 512-elem subblock

    f32x4 acc[4][4] = {};
    const int nk = K / BK;

    stage(0, 0); stage(1, 1); stage(2, 2);

    for (int t = 0; t < nk; ++t) {
        const int rem = nk - 1 - t;       // stages still outstanding beyond t
        if (rem >= 2)      asm volatile("s_waitcnt vmcnt(10)" ::: "memory");
        else if (rem == 1) asm volatile("s_waitcnt vmcnt(5)"  ::: "memory");
        else               asm volatile("s_waitcnt vmcnt(0)"  ::: "memory");
        __builtin_amdgcn_s_barrier();
        __builtin_amdgcn_sched_barrier(0);   // fence: nothing crosses the barrier

        const __bf16* as  = As[t & 3];
        const __bf16* wsc = Ws[t & 3];
        v8bf a[4], b[4];
#pragma unroll
        for (int m = 0; m < 4; ++m) a[m] = *(const v8bf*)&as[(wid * 4 + m) * 512 + off];
#pragma unroll
        for (int n = 0; n < 4; ++n) b[n] = *(const v8bf*)&wsc[n * 512 + off];

        if (t + 3 < nk) stage((t + 3) & 3, t + 3);   // distance-3 prefetch

        __builtin_amdgcn_s_setprio(1);
#pragma unroll
        for (int m = 0; m < 4; ++m)
#pragma unroll
            for (int n = 0; n < 4; ++n)
                acc[m][n] = __builtin_amdgcn_mfma_f32_16x16x32_bf16(a[m], b[n], acc[m][n], 0, 0, 0);
        __builtin_amdgcn_s_setprio(0);
    }

#pragma unroll
    for (int m = 0; m < 4; ++m)
#pragma unroll
        for (int n = 0; n < 4; ++n)
#pragma unroll
            for (int rr = 0; rr < 4; ++rr) {
                int row = m0 + wid * 64 + m * 16 + kh * 4 + rr;
                int col = n0 + n * 16 + lr;
                float vv = acc[m][n][rr] + bias[col];
                if (EPI == 1) vv += (float)add[(size_t)row * N + col];
                if (EPI == 2) vv = fast_gelu(vv);
                C[(size_t)row * N + col] = (OutT)vv;
            }
}

// ---------------- Windowed attention: one wave per (head, window) ----------------
__global__ __launch_bounds__(64)
void attn_kernel(const __bf16* __restrict__ qkv, const float* __restrict__ biases,
                 const int* __restrict__ bidx, __bf16* __restrict__ out)
{
    const int head = blockIdx.x;
    const int win  = blockIdx.y;
    const int tid  = threadIdx.x;
    const int b  = win >> 4;
    const int wy = (win >> 2) & 3;
    const int wx = win & 3;
    __shared__ float kk[49][32];
    __shared__ float vv[49][32];
    const size_t hb = (size_t)head * 96;

    for (int e = tid; e < 49 * 32; e += 64) {
        int n = e >> 5, d = e & 31;
        int iy = n / 7, ix = n - iy * 7;
        size_t t = (size_t)b * 784 + (size_t)(wy * 7 + iy) * 28 + wx * 7 + ix;
        const __bf16* p = qkv + t * QKVD + hb;
        kk[n][d] = (float)p[32 + d];
        vv[n][d] = (float)p[64 + d];
    }
    float q[32];
    size_t tmine = 0;
    if (tid < 49) {
        int iy = tid / 7, ix = tid - iy * 7;
        tmine = (size_t)b * 784 + (size_t)(wy * 7 + iy) * 28 + wx * 7 + ix;
        const __bf16* p = qkv + tmine * QKVD + hb;
#pragma unroll
        for (int d = 0; d < 32; ++d) q[d] = (float)p[d];
    }
    __syncthreads();
    if (tid >= 49) return;

    const float scale = 0.17677669529663687f;
    float s[49];
    float mx = -1e30f;
    const int*   brow = bidx + tid * 49;
    const float* bh   = biases + head * 49;
#pragma unroll
    for (int m = 0; m < 49; ++m) {
        float dot = 0.f;
#pragma unroll
        for (int d = 0; d < 32; ++d) dot += q[d] * kk[m][d];
        float val = dot * scale + bh[brow[m]];
        s[m] = val;
        mx = fmaxf(mx, val);
    }
    float sum = 0.f;
#pragma unroll
    for (int m = 0; m < 49; ++m) { float e = __expf(s[m] - mx); s[m] = e; sum += e; }
    const float rs = 1.0f / sum;

    __bf16* op = out + tmine * CDIM + (size_t)head * 32;
#pragma unroll
    for (int d = 0; d < 32; ++d) {
        float a = 0.f;
#pragma unroll
        for (int m = 0; m < 49; ++m) a += s[m] * vv[m][d];
        op[d] = (__bf16)(a * rs);
    }
}

// ------- Depthwise 3x3 conv + folded BN, vectorized: 8 channels/thread -------
__global__ __launch_bounds__(256)
void conv_bn_v(const __bf16* __restrict__ xin, const __bf16* __restrict__ wt,
               const float* __restrict__ bias2, __bf16* __restrict__ xout)
{
    const size_t gt = (size_t)blockIdx.x * 256 + threadIdx.x;
    const int g = (int)(gt % 72);
    const size_t p = gt / 72;
    const int bimg = (int)(p / 784);
    const int pix  = (int)(p - (size_t)bimg * 784);
    const int y = pix / 28, xx = pix - y * 28;
    const int c0 = g * 8;

    float acc[8];
    {
        f32x4 b0 = *(const f32x4*)&bias2[c0];
        f32x4 b1 = *(const f32x4*)&bias2[c0 + 4];
#pragma unroll
        for (int jj = 0; jj < 4; ++jj) { acc[jj] = b0[jj]; acc[4 + jj] = b1[jj]; }
    }
#pragma unroll
    for (int dy = 0; dy < 3; ++dy) {
        int ny = y + dy - 1;
        if (ny < 0 || ny >= 28) continue;
#pragma unroll
        for (int dx = 0; dx < 3; ++dx) {
            int nx = xx + dx - 1;
            if (nx < 0 || nx >= 28) continue;
            v8bf xv = *(const v8bf*)&xin[((size_t)bimg * 784 + ny * 28 + nx) * CDIM + c0];
            v8bf wv = *(const v8bf*)&wt[(dy * 3 + dx) * CDIM + c0];
#pragma unroll
            for (int jj = 0; jj < 8; ++jj) acc[jj] += (float)xv[jj] * (float)wv[jj];
        }
    }
    v8bf o;
#pragma unroll
    for (int jj = 0; jj < 8; ++jj) o[jj] = (__bf16)acc[jj];
    *(v8bf*)&xout[p * CDIM + c0] = o;
}

extern "C" void kernel_launch(void* const* d_in, const int* in_sizes, int n_in,
                              void* d_out, int out_size, void* d_ws, size_t ws_size,
                              hipStream_t stream)
{
    (void)in_sizes; (void)n_in; (void)out_size; (void)ws_size;
    const float* x          = (const float*)d_in[0];
    const float* gamma_a    = (const float*)d_in[1];
    const float* beta_a     = (const float*)d_in[2];
    const float* qkv_w      = (const float*)d_in[3];
    const float* qkv_b      = (const float*)d_in[4];
    const float* proj_w     = (const float*)d_in[5];
    const float* proj_b     = (const float*)d_in[6];
    const float* attn_bias  = (const float*)d_in[7];
    const float* conv_w     = (const float*)d_in[8];
    const float* bn_g       = (const float*)d_in[9];
    const float* bn_b       = (const float*)d_in[10];
    const float* bn_m       = (const float*)d_in[11];
    const float* bn_v       = (const float*)d_in[12];
    const float* gamma_m    = (const float*)d_in[13];
    const float* beta_m     = (const float*)d_in[14];
    const float* fc1_w      = (const float*)d_in[15];
    const float* fc1_b      = (const float*)d_in[16];
    const float* fc2_w      = (const float*)d_in[17];
    const float* fc2_b      = (const float*)d_in[18];
    const int*   bidx       = (const int*)d_in[19];

    const size_t T = TOKENS;
    __bf16* ws     = (__bf16*)d_ws;
    __bf16* hbuf   = ws;
    __bf16* qkvbuf = ws + T * 576;
    __bf16* aout   = ws;                 // reuse hbuf
    __bf16* x2     = ws + T * 2304;
    __bf16* x3     = x2 + T * 576;
    __bf16* lnm    = x2;                 // reuse (x2 dead after conv_bn)
    __bf16* f1     = ws;                 // reuse R0
    __bf16* wq     = x3 + T * 576;                   // qkv_w bf16  [1728*576]
    __bf16* wp     = wq + (size_t)QKVD * CDIM;       // proj_w bf16 [576*576]
    __bf16* w1     = wp + (size_t)CDIM * CDIM;       // fc1_w bf16  [2304*576]
    __bf16* w2     = w1 + (size_t)2304 * CDIM;       // fc2_w bf16  [576*2304]
    __bf16* wt     = w2 + (size_t)CDIM * 2304;       // conv wt [9][576]
    float*  bias2  = (float*)(wt + 9 * CDIM);        // conv bias [576]
    float*  outp   = (float*)d_out;

    cast_kernel<<<dim3((QKVD * CDIM) / 1024), 256, 0, stream>>>(qkv_w, wq);
    cast_kernel<<<dim3((CDIM * CDIM) / 1024), 256, 0, stream>>>(proj_w, wp);
    cast_kernel<<<dim3((2304 * CDIM) / 1024), 256, 0, stream>>>(fc1_w, w1);
    cast_kernel<<<dim3((CDIM * 2304) / 1024), 256, 0, stream>>>(fc2_w, w2);
    conv_prep<<<dim3(9), 64, 0, stream>>>(conv_w, bn_g, bn_b, bn_m, bn_v, wt, bias2);

    ln_kernel<float><<<dim3(T / 4), 256, 0, stream>>>(x, gamma_a, beta_a, hbuf);
    gemm_bt<0, __bf16, float><<<dim3(196 * 27), 256, 0, stream>>>(
        hbuf, wq, qkv_b, nullptr, qkvbuf, QKVD, CDIM, 27);
    attn_kernel<<<dim3(NHEAD, 1024), 64, 0, stream>>>(qkvbuf, attn_bias, bidx, aout);
    gemm_bt<1, __bf16, float><<<dim3(196 * 9), 256, 0, stream>>>(
        aout, wp, proj_b, x, x2, CDIM, CDIM, 9);
    conv_bn_v<<<dim3(14112), 256, 0, stream>>>(x2, wt, bias2, x3);
    ln_kernel<__bf16><<<dim3(T / 4), 256, 0, stream>>>(x3, gamma_m, beta_m, lnm);
    gemm_bt<2, __bf16, float><<<dim3(196 * 36), 256, 0, stream>>>(
        lnm, w1, fc1_b, nullptr, f1, 2304, CDIM, 36);
    gemm_bt<1, float, __bf16><<<dim3(196 * 9), 256, 0, stream>>>(
        f1, w2, fc2_b, x3, outp, CDIM, 2304, 9);
}

// Round 9
// 1021.368 us; speedup vs baseline: 1.3110x; 1.3110x over previous
//
#include <hip/hip_runtime.h>
#include <hip/hip_bf16.h>

typedef __bf16 v8bf  __attribute__((ext_vector_type(8)));
typedef __bf16 v4bf  __attribute__((ext_vector_type(4)));
typedef float  f32x4 __attribute__((ext_vector_type(4)));
typedef float  f32x8 __attribute__((ext_vector_type(8)));

#define TOKENS 50176
#define CDIM   576
#define NHEAD  18
#define QKVD   1728

// async global->LDS, 16B per lane; LDS dest = wave-uniform base + lane*16
__device__ __forceinline__ void gld16(const __bf16* g, __bf16* l)
{
    __builtin_amdgcn_global_load_lds(
        (const __attribute__((address_space(1))) void*)g,
        (__attribute__((address_space(3))) void*)l,
        16, 0, 0);
}

// exact-GELU via Abramowitz-Stegun 7.1.26 erf (|err| <= 1.5e-7, below bf16 eps)
__device__ __forceinline__ float fast_gelu(float x)
{
    const float z  = x * 0.70710678118654752f;
    const float az = fabsf(z);
    const float t  = __frcp_rn(1.0f + 0.3275911f * az);
    float p = 1.061405429f;
    p = p * t - 1.453152027f;
    p = p * t + 1.421413741f;
    p = p * t - 0.284496736f;
    p = p * t + 0.254829592f;
    const float e   = __expf(-z * z);
    float erfv = 1.0f - p * t * e;
    erfv = copysignf(erfv, z);
    return 0.5f * x * (1.0f + erfv);
}

// ---------------- f32 -> bf16 cast (weights), 4 elems/thread ----------------
__global__ __launch_bounds__(256)
void cast_kernel(const float* __restrict__ in, __bf16* __restrict__ out)
{
    const size_t i = ((size_t)blockIdx.x * 256 + threadIdx.x) * 4;
    f32x4 v = *(const f32x4*)&in[i];
    v4bf o;
#pragma unroll
    for (int j = 0; j < 4; ++j) o[j] = (__bf16)v[j];
    *(v4bf*)&out[i] = o;
}

// ------- conv weight prep: fold BN scale into weights, make [9][576] bf16 -------
__global__ __launch_bounds__(64)
void conv_prep(const float* __restrict__ w, const float* __restrict__ bg,
               const float* __restrict__ bb, const float* __restrict__ bm,
               const float* __restrict__ bv, __bf16* __restrict__ wt,
               float* __restrict__ bias2)
{
    const int c = blockIdx.x * 64 + threadIdx.x;   // 576
    const float inv = rsqrtf(bv[c] + 1e-5f) * bg[c];
#pragma unroll
    for (int t = 0; t < 9; ++t) wt[t * CDIM + c] = (__bf16)(w[c * 9 + t] * inv);
    bias2[c] = bb[c] - bm[c] * inv;
}

// ---------------- LayerNorm: one wave per token, C=576; InT in, bf16 out ----
template<typename InT>
__global__ __launch_bounds__(256)
void ln_kernel(const InT* __restrict__ x, const float* __restrict__ g,
               const float* __restrict__ b, __bf16* __restrict__ out)
{
    const int lane = threadIdx.x & 63;
    const int wid  = threadIdx.x >> 6;
    const size_t t = (size_t)blockIdx.x * 4 + wid;
    const InT* row = x + t * CDIM;

    float v[16];
    float sum = 0.f, sq = 0.f;
    if constexpr (sizeof(InT) == 2) {
        v8bf d0 = *(const v8bf*)&row[(size_t)lane * 8];
#pragma unroll
        for (int j = 0; j < 8; ++j) { float f = (float)d0[j]; v[j] = f; sum += f; sq += f * f; }
    } else {
        f32x8 d0 = *(const f32x8*)&row[(size_t)lane * 8];
#pragma unroll
        for (int j = 0; j < 8; ++j) { float f = d0[j]; v[j] = f; sum += f; sq += f * f; }
    }
    if (lane < 8) {
        if constexpr (sizeof(InT) == 2) {
            v8bf d1 = *(const v8bf*)&row[(size_t)(lane + 64) * 8];
#pragma unroll
            for (int j = 0; j < 8; ++j) { float f = (float)d1[j]; v[8 + j] = f; sum += f; sq += f * f; }
        } else {
            f32x8 d1 = *(const f32x8*)&row[(size_t)(lane + 64) * 8];
#pragma unroll
            for (int j = 0; j < 8; ++j) { float f = d1[j]; v[8 + j] = f; sum += f; sq += f * f; }
        }
    }
#pragma unroll
    for (int o = 32; o >= 1; o >>= 1) {
        sum += __shfl_xor(sum, o, 64);
        sq  += __shfl_xor(sq,  o, 64);
    }
    const float mean = sum * (1.0f / CDIM);
    const float rstd = rsqrtf(sq * (1.0f / CDIM) - mean * mean + 1e-5f);

    {
        int c0 = lane * 8;
        v8bf o0;
#pragma unroll
        for (int j = 0; j < 8; ++j)
            o0[j] = (__bf16)((v[j] - mean) * rstd * g[c0 + j] + b[c0 + j]);
        *(v8bf*)&out[t * CDIM + c0] = o0;
    }
    if (lane < 8) {
        int c0 = (lane + 64) * 8;
        v8bf o1;
#pragma unroll
        for (int j = 0; j < 8; ++j)
            o1[j] = (__bf16)((v[8 + j] - mean) * rstd * g[c0 + j] + b[c0 + j]);
        *(v8bf*)&out[t * CDIM + c0] = o1;
    }
}

// ------- GEMM: C[M][N] = A[M][K] @ W[N][K]^T + bias, optional epilogue -------
// m201-style phase template, adapted: tile 256x192, BK=32, 512 thr / 8 waves
// (2M x 4N), per-wave output 128x48 (8x3 frags). Ring-4 LDS (112 KB),
// stage-ahead-2, per-wave counted vmcnt (loads/tile: 4 for waves 0-5, 2 for
// waves 6-7 which only stage A). Per K-tile: vmcnt+barrier certify tile t
// (staged 2 tiles earlier -> loads span multiple barriers), then two phases:
// {7 ds_read || stage A(t+2)} MFMA*12 barrier {4 ds_read || stage B(t+2)}
// MFMA*12. Subtiled 1KB LDS cells (16 rows x 32 k): conflict-free ds_read_b128,
// linear gld16 dest. 192 divides all N (576/1728/2304): no raggedness.
// EPI: 0 = none, 1 = += add[M][N], 2 = exact GELU
template<int EPI, typename OutT, typename AddT>
__global__ __launch_bounds__(512, 1)
void gemm_bt(const __bf16* __restrict__ A, const __bf16* __restrict__ W,
             const float* __restrict__ bias, const AddT* __restrict__ add,
             OutT* __restrict__ C, int N, int K, int nN)
{
    constexpr int BM = 256, BN = 192, BK = 32;
    constexpr int ASZ = BM * BK;          // 8192 elems
    constexpr int BSZ = BN * BK;          // 6144 elems
    __shared__ __bf16 L[4][ASZ + BSZ];    // 4 x 28 KB = 112 KB
    const int tid = threadIdx.x, lane = tid & 63, wid = tid >> 6;
    const int lr = lane & 15, kh = lane >> 4;
    const int wm = wid >> 2, wn = wid & 3;       // wave grid 2(M) x 4(N)

    // XCD-chunked bijective swizzle (m204), N-fastest decode
    const int nwg = gridDim.x, bid = blockIdx.x;
    const int q = nwg >> 3, r = nwg & 7;
    const int xcd = bid & 7, jc = bid >> 3;
    const int wgid = (xcd < r ? xcd * (q + 1) : r * (q + 1) + (xcd - r) * q) + jc;
    const int mblk = wgid / nN, nblk = wgid - mblk * nN;
    const int m0 = mblk * BM, n0 = nblk * BN;

    // staging sources: wave wid stages A rows [wid*32,+32); waves 0-5 stage
    // B rows [wid*32,+32) (12 cells of 16 rows cover BN=192)
    const __bf16* pA = A + (size_t)(m0 + wid * 32 + lr) * K + kh * 8;
    const __bf16* pW = W + (size_t)(n0 + (wid < 6 ? wid : 0) * 32 + lr) * K + kh * 8;

    auto stageA = [&](int s, int kt) {
#pragma unroll
        for (int i = 0; i < 2; ++i)
            gld16(pA + (size_t)(i * 16) * K + kt * BK, &L[s][(wid * 2 + i) * 512]);
    };
    auto stageB = [&](int s, int kt) {
        if (wid < 6) {
#pragma unroll
            for (int i = 0; i < 2; ++i)
                gld16(pW + (size_t)(i * 16) * K + kt * BK,
                      &L[s][ASZ + (wid * 2 + i) * 512]);
        }
    };

    const int off = lane * 8;   // elems; lane-linear 16B -> conflict-free

    f32x4 acc[8][3] = {};
    const int NT = K / BK;

    stageA(0, 0); stageB(0, 0);
    stageA(1, 1); stageB(1, 1);

    for (int t = 0; t < NT; ++t) {
        // certify tile t (own-wave loads), then barrier syncs all waves
        if (t + 1 < NT) {
            if (wid < 6) asm volatile("s_waitcnt vmcnt(4)" ::: "memory");
            else         asm volatile("s_waitcnt vmcnt(2)" ::: "memory");
        } else {
            asm volatile("s_waitcnt vmcnt(0)" ::: "memory");
        }
        __builtin_amdgcn_s_barrier();

        const __bf16* Ls = L[t & 3];
        v8bf bfr[3], afr[4];

        // ---- phase 0: b[0..2] + a[0..3] reads, stage A(t+2), 12 MFMA ----
#pragma unroll
        for (int nf = 0; nf < 3; ++nf)
            bfr[nf] = *(const v8bf*)&Ls[ASZ + (wn * 3 + nf) * 512 + off];
#pragma unroll
        for (int mf = 0; mf < 4; ++mf)
            afr[mf] = *(const v8bf*)&Ls[(wm * 8 + mf) * 512 + off];

        if (t + 2 < NT) stageA((t + 2) & 3, t + 2);

        __builtin_amdgcn_s_setprio(1);
#pragma unroll
        for (int mf = 0; mf < 4; ++mf)
#pragma unroll
            for (int nf = 0; nf < 3; ++nf)
                acc[mf][nf] = __builtin_amdgcn_mfma_f32_16x16x32_bf16(
                    afr[mf], bfr[nf], acc[mf][nf], 0, 0, 0);
        __builtin_amdgcn_s_setprio(0);
        __builtin_amdgcn_s_barrier();

        // ---- phase 1: a[4..7] reads, stage B(t+2), 12 MFMA ----
#pragma unroll
        for (int mf = 0; mf < 4; ++mf)
            afr[mf] = *(const v8bf*)&Ls[(wm * 8 + 4 + mf) * 512 + off];

        if (t + 2 < NT) stageB((t + 2) & 3, t + 2);

        __builtin_amdgcn_s_setprio(1);
#pragma unroll
        for (int mf = 0; mf < 4; ++mf)
#pragma unroll
            for (int nf = 0; nf < 3; ++nf)
                acc[4 + mf][nf] = __builtin_amdgcn_mfma_f32_16x16x32_bf16(
                    afr[mf], bfr[nf], acc[4 + mf][nf], 0, 0, 0);
        __builtin_amdgcn_s_setprio(0);
    }

    // ---- epilogue ----
#pragma unroll
    for (int mf = 0; mf < 8; ++mf)
#pragma unroll
        for (int nf = 0; nf < 3; ++nf)
#pragma unroll
            for (int rr = 0; rr < 4; ++rr) {
                int row = m0 + wm * 128 + mf * 16 + kh * 4 + rr;
                int col = n0 + wn * 48 + nf * 16 + lr;
                float vv = acc[mf][nf][rr] + bias[col];
                if (EPI == 1) vv += (float)add[(size_t)row * N + col];
                if (EPI == 2) vv = fast_gelu(vv);
                C[(size_t)row * N + col] = (OutT)vv;
            }
}

// ---------------- Windowed attention: one wave per (head, window) ----------------
__global__ __launch_bounds__(64)
void attn_kernel(const __bf16* __restrict__ qkv, const float* __restrict__ biases,
                 const int* __restrict__ bidx, __bf16* __restrict__ out)
{
    const int head = blockIdx.x;
    const int win  = blockIdx.y;
    const int tid  = threadIdx.x;
    const int b  = win >> 4;
    const int wy = (win >> 2) & 3;
    const int wx = win & 3;
    __shared__ float kk[49][32];
    __shared__ float vv[49][32];
    const size_t hb = (size_t)head * 96;

    for (int e = tid; e < 49 * 32; e += 64) {
        int n = e >> 5, d = e & 31;
        int iy = n / 7, ix = n - iy * 7;
        size_t t = (size_t)b * 784 + (size_t)(wy * 7 + iy) * 28 + wx * 7 + ix;
        const __bf16* p = qkv + t * QKVD + hb;
        kk[n][d] = (float)p[32 + d];
        vv[n][d] = (float)p[64 + d];
    }
    float q[32];
    size_t tmine = 0;
    if (tid < 49) {
        int iy = tid / 7, ix = tid - iy * 7;
        tmine = (size_t)b * 784 + (size_t)(wy * 7 + iy) * 28 + wx * 7 + ix;
        const __bf16* p = qkv + tmine * QKVD + hb;
#pragma unroll
        for (int d = 0; d < 32; ++d) q[d] = (float)p[d];
    }
    __syncthreads();
    if (tid >= 49) return;

    const float scale = 0.17677669529663687f;
    float s[49];
    float mx = -1e30f;
    const int*   brow = bidx + tid * 49;
    const float* bh   = biases + head * 49;
#pragma unroll
    for (int m = 0; m < 49; ++m) {
        float dot = 0.f;
#pragma unroll
        for (int d = 0; d < 32; ++d) dot += q[d] * kk[m][d];
        float val = dot * scale + bh[brow[m]];
        s[m] = val;
        mx = fmaxf(mx, val);
    }
    float sum = 0.f;
#pragma unroll
    for (int m = 0; m < 49; ++m) { float e = __expf(s[m] - mx); s[m] = e; sum += e; }
    const float rs = 1.0f / sum;

    __bf16* op = out + tmine * CDIM + (size_t)head * 32;
#pragma unroll
    for (int d = 0; d < 32; ++d) {
        float a = 0.f;
#pragma unroll
        for (int m = 0; m < 49; ++m) a += s[m] * vv[m][d];
        op[d] = (__bf16)(a * rs);
    }
}

// ------- Depthwise 3x3 conv + folded BN, vectorized: 8 channels/thread -------
__global__ __launch_bounds__(256)
void conv_bn_v(const __bf16* __restrict__ xin, const __bf16* __restrict__ wt,
               const float* __restrict__ bias2, __bf16* __restrict__ xout)
{
    const size_t gt = (size_t)blockIdx.x * 256 + threadIdx.x;
    const int g = (int)(gt % 72);
    const size_t p = gt / 72;
    const int bimg = (int)(p / 784);
    const int pix  = (int)(p - (size_t)bimg * 784);
    const int y = pix / 28, xx = pix - y * 28;
    const int c0 = g * 8;

    float acc[8];
    {
        f32x4 b0 = *(const f32x4*)&bias2[c0];
        f32x4 b1 = *(const f32x4*)&bias2[c0 + 4];
#pragma unroll
        for (int jj = 0; jj < 4; ++jj) { acc[jj] = b0[jj]; acc[4 + jj] = b1[jj]; }
    }
#pragma unroll
    for (int dy = 0; dy < 3; ++dy) {
        int ny = y + dy - 1;
        if (ny < 0 || ny >= 28) continue;
#pragma unroll
        for (int dx = 0; dx < 3; ++dx) {
            int nx = xx + dx - 1;
            if (nx < 0 || nx >= 28) continue;
            v8bf xv = *(const v8bf*)&xin[((size_t)bimg * 784 + ny * 28 + nx) * CDIM + c0];
            v8bf wv = *(const v8bf*)&wt[(dy * 3 + dx) * CDIM + c0];
#pragma unroll
            for (int jj = 0; jj < 8; ++jj) acc[jj] += (float)xv[jj] * (float)wv[jj];
        }
    }
    v8bf o;
#pragma unroll
    for (int jj = 0; jj < 8; ++jj) o[jj] = (__bf16)acc[jj];
    *(v8bf*)&xout[p * CDIM + c0] = o;
}

extern "C" void kernel_launch(void* const* d_in, const int* in_sizes, int n_in,
                              void* d_out, int out_size, void* d_ws, size_t ws_size,
                              hipStream_t stream)
{
    (void)in_sizes; (void)n_in; (void)out_size; (void)ws_size;
    const float* x          = (const float*)d_in[0];
    const float* gamma_a    = (const float*)d_in[1];
    const float* beta_a     = (const float*)d_in[2];
    const float* qkv_w      = (const float*)d_in[3];
    const float* qkv_b      = (const float*)d_in[4];
    const float* proj_w     = (const float*)d_in[5];
    const float* proj_b     = (const float*)d_in[6];
    const float* attn_bias  = (const float*)d_in[7];
    const float* conv_w     = (const float*)d_in[8];
    const float* bn_g       = (const float*)d_in[9];
    const float* bn_b       = (const float*)d_in[10];
    const float* bn_m       = (const float*)d_in[11];
    const float* bn_v       = (const float*)d_in[12];
    const float* gamma_m    = (const float*)d_in[13];
    const float* beta_m     = (const float*)d_in[14];
    const float* fc1_w      = (const float*)d_in[15];
    const float* fc1_b      = (const float*)d_in[16];
    const float* fc2_w      = (const float*)d_in[17];
    const float* fc2_b      = (const float*)d_in[18];
    const int*   bidx       = (const int*)d_in[19];

    const size_t T = TOKENS;
    __bf16* ws     = (__bf16*)d_ws;
    __bf16* hbuf   = ws;
    __bf16* qkvbuf = ws + T * 576;
    __bf16* aout   = ws;                 // reuse hbuf
    __bf16* x2     = ws + T * 2304;
    __bf16* x3     = x2 + T * 576;
    __bf16* lnm    = x2;                 // reuse (x2 dead after conv_bn)
    __bf16* f1     = ws;                 // reuse R0
    __bf16* wq     = x3 + T * 576;                   // qkv_w bf16  [1728*576]
    __bf16* wp     = wq + (size_t)QKVD * CDIM;       // proj_w bf16 [576*576]
    __bf16* w1     = wp + (size_t)CDIM * CDIM;       // fc1_w bf16  [2304*576]
    __bf16* w2     = w1 + (size_t)2304 * CDIM;       // fc2_w bf16  [576*2304]
    __bf16* wt     = w2 + (size_t)CDIM * 2304;       // conv wt [9][576]
    float*  bias2  = (float*)(wt + 9 * CDIM);        // conv bias [576]
    float*  outp   = (float*)d_out;

    cast_kernel<<<dim3((QKVD * CDIM) / 1024), 256, 0, stream>>>(qkv_w, wq);
    cast_kernel<<<dim3((CDIM * CDIM) / 1024), 256, 0, stream>>>(proj_w, wp);
    cast_kernel<<<dim3((2304 * CDIM) / 1024), 256, 0, stream>>>(fc1_w, w1);
    cast_kernel<<<dim3((CDIM * 2304) / 1024), 256, 0, stream>>>(fc2_w, w2);
    conv_prep<<<dim3(9), 64, 0, stream>>>(conv_w, bn_g, bn_b, bn_m, bn_v, wt, bias2);

    ln_kernel<float><<<dim3(T / 4), 256, 0, stream>>>(x, gamma_a, beta_a, hbuf);
    gemm_bt<0, __bf16, float><<<dim3(196 * 9), 512, 0, stream>>>(
        hbuf, wq, qkv_b, nullptr, qkvbuf, QKVD, CDIM, 9);
    attn_kernel<<<dim3(NHEAD, 1024), 64, 0, stream>>>(qkvbuf, attn_bias, bidx, aout);
    gemm_bt<1, __bf16, float><<<dim3(196 * 3), 512, 0, stream>>>(
        aout, wp, proj_b, x, x2, CDIM, CDIM, 3);
    conv_bn_v<<<dim3(14112), 256, 0, stream>>>(x2, wt, bias2, x3);
    ln_kernel<__bf16><<<dim3(T / 4), 256, 0, stream>>>(x3, gamma_m, beta_m, lnm);
    gemm_bt<2, __bf16, float><<<dim3(196 * 12), 512, 0, stream>>>(
        lnm, w1, fc1_b, nullptr, f1, 2304, CDIM, 12);
    gemm_bt<1, float, __bf16><<<dim3(196 * 3), 512, 0, stream>>>(
        f1, w2, fc2_b, x3, outp, CDIM, 2304, 3);
}